// Round 6
// baseline (203.100 us; speedup 1.0000x reference)
//
#include <hip/hip_runtime.h>
#include <hip/hip_bf16.h>

#define Bn 4
#define Sn 4096
#define Dn 64

typedef short          s16x8 __attribute__((ext_vector_type(8)));
typedef unsigned short u16x8 __attribute__((ext_vector_type(8)));
typedef float          f32x4 __attribute__((ext_vector_type(4)));

__device__ __forceinline__ unsigned short f2bf(float f) {
    unsigned u = __float_as_uint(f);
    u = u + 0x7fffu + ((u >> 16) & 1u);   // RNE
    return (unsigned short)(u >> 16);
}
__device__ __forceinline__ float bf2f(unsigned short h) {
    return __uint_as_float(((unsigned)h) << 16);
}
__device__ __forceinline__ unsigned long long pack4(float4 x) {
    return (unsigned long long)f2bf(x.x)
         | ((unsigned long long)f2bf(x.y) << 16)
         | ((unsigned long long)f2bf(x.z) << 32)
         | ((unsigned long long)f2bf(x.w) << 48);
}

// ---------------------------------------------------------------------------
// Kernel 1 (init): 9 blocks x 256 threads.
//   blocks 0..7 : pack pad_mask into padbits (32 words of 64 cols each).
//                 dtype detection (uint8 vs int32 bool storage) per block,
//                 window restricted to the first 16KB (safe in both interps).
//   block 8     : zero meanVsum (256 floats)  [replaces hipMemsetAsync].
// ---------------------------------------------------------------------------
__global__ void LPSAN_init_kernel(const unsigned char* pm, unsigned long long* padbits,
                                  float* meanVsum) {
    const int k = blockIdx.x, t = threadIdx.x;
    if (k == 8) { meanVsum[t] = 0.f; return; }

    __shared__ unsigned nzs;
    if (t == 0) nzs = 0u;
    __syncthreads();
    { // detection: bytes [k*2048, (k+1)*2048) -- inside first 16KB, safe always
        const uint2* p2 = (const uint2*)(pm + k * 2048);
        uint2 x = p2[t];
        unsigned acc = (x.x & 0xFFFFFF00u) | (x.y & 0xFFFFFF00u);
        if (acc) atomicOr(&nzs, 1u);
    }
    __syncthreads();
    if (t >= 32) return;
    const int wi = k * 32 + t;              // padbits word index
    unsigned long long bits = 0ull;
    if (nzs) {                              // uint8 storage: 64 bytes
        const uint4* p4 = (const uint4*)(pm + wi * 64);
        #pragma unroll
        for (int q = 0; q < 4; ++q) {
            uint4 x = p4[q];
            unsigned w[4] = { x.x, x.y, x.z, x.w };
            #pragma unroll
            for (int wj = 0; wj < 4; ++wj)
                #pragma unroll
                for (int bb = 0; bb < 4; ++bb)
                    bits |= (unsigned long long)(((w[wj] >> (8 * bb)) & 0xFFu) != 0u)
                            << (q * 16 + wj * 4 + bb);
        }
    } else {                                // int32 storage: 64 ints
        const uint4* p4 = (const uint4*)pm + wi * 16;
        #pragma unroll
        for (int q = 0; q < 16; ++q) {
            uint4 x = p4[q];
            bits |= (unsigned long long)(x.x != 0u) << (q * 4);
            bits |= (unsigned long long)(x.y != 0u) << (q * 4 + 1);
            bits |= (unsigned long long)(x.z != 0u) << (q * 4 + 2);
            bits |= (unsigned long long)(x.w != 0u) << (q * 4 + 3);
        }
    }
    padbits[wi] = bits;
}

// ---------------------------------------------------------------------------
// Kernel 2: MFMA QKV projection.  64 rows/block, 256 blocks, 4 waves x 16
// rows.  E and W staged as bf16 in LDS with XOR swizzle ^((row&7)<<4); 8
// MFMA (16x16x32) per matrix per wave.  Epilogue: bias+modulation in fp32,
// routed through a padded LDS buffer for coalesced 16B global stores.
//   Qb = (E@Wq^T+bq)*0.125 ; Kb = (.)*P_K ; Vt[b][d][s] = (.)*P_V (transposed)
// Also accumulates meanVsum[b*64+d] = sum_s V_p.
// ---------------------------------------------------------------------------
__global__ void LPSAN_proj_kernel(
    const float* __restrict__ E, const float* __restrict__ PK, const float* __restrict__ PV,
    const float* __restrict__ Wq, const float* __restrict__ bq,
    const float* __restrict__ Wk, const float* __restrict__ bk,
    const float* __restrict__ Wv, const float* __restrict__ bv,
    unsigned short* __restrict__ Qb, unsigned short* __restrict__ Kb,
    unsigned short* __restrict__ Vt, float* __restrict__ meanVsum)
{
    __shared__ unsigned short Ebf[4096];        // [64][64] bf16, swizzled (8KB)
    __shared__ unsigned short Wbf[3][4096];     // swizzled (24KB)
    __shared__ unsigned short Tbuf[64 * 72];    // 144B rows, transpose staging (9KB)

    const int t = threadIdx.x;                  // 256 threads
    const int r0 = blockIdx.x * 64;
    const int b  = r0 >> 12;
    const int s0 = r0 & (Sn - 1);
    const int w = t >> 6, lane = t & 63;
    const int fq = lane >> 4, fr = lane & 15;

    { // stage E and W: fp32 -> bf16, swizzled 8B writes
        const float4* Eg = (const float4*)(E + (size_t)r0 * 64);
        #pragma unroll
        for (int v = 0; v < 4; ++v) {
            int f = t + v * 256;
            float4 x = Eg[f];
            int row = f >> 4, c4 = f & 15;
            *(unsigned long long*)((char*)Ebf + row * 128 + ((c4 * 8) ^ ((row & 7) << 4))) = pack4(x);
        }
        #pragma unroll
        for (int m = 0; m < 3; ++m) {
            const float4* Wg = (const float4*)(m == 0 ? Wq : m == 1 ? Wk : Wv);
            #pragma unroll
            for (int v = 0; v < 4; ++v) {
                int f = t + v * 256;
                float4 x = Wg[f];
                int row = f >> 4, c4 = f & 15;
                *(unsigned long long*)((char*)Wbf[m] + row * 128 + ((c4 * 8) ^ ((row & 7) << 4))) = pack4(x);
            }
        }
    }
    __syncthreads();

    // A-frags: E[row = w*16+fr][k = ks*32 + fq*8+i]
    const int  arow = w * 16 + fr;
    const int  swz  = (fr & 7) << 4;            // (arow&7) == (fr&7) == (ct*16+fr)&7
    const char* Ec = (const char*)Ebf;
    const s16x8 ea0 = *(const s16x8*)(Ec + arow * 128 + ((fq * 16) ^ swz));
    const s16x8 ea1 = *(const s16x8*)(Ec + arow * 128 + ((64 + fq * 16) ^ swz));

    const int sl0 = w * 16 + fq * 4;            // lane's first local output row

    for (int m = 0; m < 3; ++m) {
        const char*  Wc   = (const char*)Wbf[m];
        const float* bias = (m == 0) ? bq : (m == 1) ? bk : bv;

        f32x4 acc[4];
        #pragma unroll
        for (int ct = 0; ct < 4; ++ct) {        // B-frag: W[j=ct*16+fr][k=fq*8+i]
            const int brow = ct * 16 + fr;
            s16x8 b0 = *(const s16x8*)(Wc + brow * 128 + ((fq * 16) ^ swz));
            s16x8 b1 = *(const s16x8*)(Wc + brow * 128 + ((64 + fq * 16) ^ swz));
            f32x4 z = f32x4{0.f, 0.f, 0.f, 0.f};
            z = __builtin_amdgcn_mfma_f32_16x16x32_bf16(ea0, b0, z, 0, 0, 0);
            z = __builtin_amdgcn_mfma_f32_16x16x32_bf16(ea1, b1, z, 0, 0, 0);
            acc[ct] = z;
        }

        if (m < 2) {                            // Q / K: Tbuf as [s][j]
            #pragma unroll
            for (int ct = 0; ct < 4; ++ct) {
                const int j = ct * 16 + fr;
                const float bb = bias[j];
                if (m == 0) {
                    #pragma unroll
                    for (int r = 0; r < 4; ++r)
                        Tbuf[(sl0 + r) * 72 + j] = f2bf((acc[ct][r] + bb) * 0.125f);
                } else {
                    #pragma unroll
                    for (int r = 0; r < 4; ++r) {
                        float mod = PK[(size_t)(r0 + sl0 + r) * 64 + j];
                        Tbuf[(sl0 + r) * 72 + j] = f2bf((acc[ct][r] + bb) * mod);
                    }
                }
            }
            __syncthreads();
            { // coalesced read-back + 16B global stores
                unsigned short* dst = (m == 0 ? Qb : Kb)
                    + (size_t)(b * Sn + s0 + (t >> 2)) * 64 + (t & 3) * 16;
                u16x8 o0 = *(const u16x8*)&Tbuf[(t >> 2) * 72 + (t & 3) * 16];
                u16x8 o1 = *(const u16x8*)&Tbuf[(t >> 2) * 72 + (t & 3) * 16 + 8];
                *(u16x8*)dst = o0;
                *(u16x8*)(dst + 8) = o1;
            }
            __syncthreads();
        } else {                                // V: Tbuf as [d][s], packed b64 writes
            #pragma unroll
            for (int ct = 0; ct < 4; ++ct) {
                const int j = ct * 16 + fr;
                const float bb = bias[j];
                unsigned long long pk = 0;
                #pragma unroll
                for (int r = 0; r < 4; ++r) {
                    float mod = PV[(size_t)(r0 + sl0 + r) * 64 + j];
                    pk |= (unsigned long long)f2bf((acc[ct][r] + bb) * mod) << (16 * r);
                }
                *(unsigned long long*)&Tbuf[j * 72 + sl0] = pk;
            }
            __syncthreads();
            {
                const int d = t >> 2, seg = t & 3;
                u16x8 o0 = *(const u16x8*)&Tbuf[d * 72 + seg * 16];
                u16x8 o1 = *(const u16x8*)&Tbuf[d * 72 + seg * 16 + 8];
                unsigned short* dst = Vt + (size_t)(b * 64 + d) * Sn + s0 + seg * 16;
                *(u16x8*)dst = o0;
                *(u16x8*)(dst + 8) = o1;
                float s = 0.f;
                #pragma unroll
                for (int i = 0; i < 8; ++i) s += bf2f(o0[i]) + bf2f(o1[i]);
                s += __shfl_xor(s, 1);
                s += __shfl_xor(s, 2);
                if ((t & 3) == 0) atomicAdd(&meanVsum[b * 64 + d], s);
            }
        }
    }
}

// ---------------------------------------------------------------------------
// Kernel 3: flash attention, split-KV, BARRIER-FREE.
// K/V are L2-resident (2MB each) -> no LDS staging: each wave loads its MFMA
// B-fragments directly from global (16B/lane; each K/V row's 64B half is
// covered by 4 lanes -> L1-friendly).  No __syncthreads / vmcnt(0) stalls;
// the 4 waves per block run independently.  Only LDS: per-wave 2KB swizzled
// P-transpose buffer (lgkmcnt(0)+sched_barrier kept).
// Static-offset softmax p = exp(s-16); row-sum l via all-ones-B MFMA;
// masked entries exactly 0.  Software pipeline per tile:
//   issue V[t] loads -> QK MFMA -> mask/exp -> P-write -> issue K[t+1] loads
//   -> P-read -> PV MFMA.
// Block = (b, qt, chunk of <=8 KV tiles), grid (288, 4), longest chunks
// dispatched first.  qt<8: final fp32 output directly; else bf16 partial + l.
// ---------------------------------------------------------------------------
__global__ __launch_bounds__(256, 4) void LPSAN_attn_kernel(
    const unsigned short* __restrict__ Qb, const unsigned short* __restrict__ Kb,
    const unsigned short* __restrict__ Vt, const unsigned long long* __restrict__ padbits,
    const float* __restrict__ meanVsum,
    unsigned short* __restrict__ Onorm, float* __restrict__ Lp, float* __restrict__ out)
{
    __shared__ unsigned short Plds[4][1024];   // per-wave P 16x64 swizzled (8KB)

    // --- map reversed blockIdx.x -> (qt, c); longest chunks first ---
    int id = 287 - blockIdx.x, g = 0, base = 0;
    while (id >= base + 8 * (g + 1)) { base += 8 * (g + 1); ++g; }
    const int rel = id - base;
    const int qt = 8 * g + rel / (g + 1);
    const int c  = rel % (g + 1);

    const int b = blockIdx.y;
    const int q0 = qt * 64;
    const int t0 = c * 8;
    const int tcnt = min(8, qt + 1 - t0);
    const int tid = threadIdx.x;
    const int w = tid >> 6, lane = tid & 63;
    const int fq = lane >> 4, fr = lane & 15;
    const int qw = q0 + w * 16;

    // per-lane row bases for direct B-frag loads
    const unsigned short* Kln = Kb + b * (Sn * Dn) + fr * 64 + fq * 8;   // + kvrow*64 (+32)
    const unsigned short* Vln = Vt + b * (Dn * Sn) + fr * Sn + fq * 8;   // + d0*Sn + kv0 (+32)

    const s16x8 qf0 = *(const s16x8*)(Qb + (b * Sn + qw + fr) * 64 + fq * 8);
    const s16x8 qf1 = *(const s16x8*)(Qb + (b * Sn + qw + fr) * 64 + 32 + fq * 8);

    s16x8 onesb;                               // all-ones bf16 B operand
    #pragma unroll
    for (int i = 0; i < 8; ++i) onesb[i] = (short)0x3F80;

    f32x4 Oa[4];
    f32x4 lacc = f32x4{0.f, 0.f, 0.f, 0.f};
    #pragma unroll
    for (int i = 0; i < 4; ++i) Oa[i] = f32x4{0.f, 0.f, 0.f, 0.f};

    char* Pw = (char*)&Plds[w][0];

    s16x8 kf[4][2], vf[4][2];

    auto LOADK = [&](int kv0) {
        #pragma unroll
        for (int tl = 0; tl < 4; ++tl) {
            const unsigned short* p = Kln + (kv0 + tl * 16) * 64;
            kf[tl][0] = *(const s16x8*)(p);
            kf[tl][1] = *(const s16x8*)(p + 32);
        }
    };
    auto LOADV = [&](int kv0) {
        #pragma unroll
        for (int dt = 0; dt < 4; ++dt) {
            const unsigned short* p = Vln + (dt * 16) * Sn + kv0;
            vf[dt][0] = *(const s16x8*)(p);
            vf[dt][1] = *(const s16x8*)(p + 32);
        }
    };

    LOADK(t0 * 64);
    for (int i = 0; i < tcnt; ++i) {
        const int t = t0 + i;
        const int kv0 = t * 64;
        const bool causal = (t == qt);

        LOADV(kv0);                            // V loads overlap QK + exp

        // --- scores: Q (16x64) x K_p^T -> 4 col-tiles of 16 ---
        f32x4 sc[4];
        #pragma unroll
        for (int tl = 0; tl < 4; ++tl) {
            f32x4 z = f32x4{0.f, 0.f, 0.f, 0.f};
            z = __builtin_amdgcn_mfma_f32_16x16x32_bf16(qf0, kf[tl][0], z, 0, 0, 0);
            z = __builtin_amdgcn_mfma_f32_16x16x32_bf16(qf1, kf[tl][1], z, 0, 0, 0);
            sc[tl] = z;
        }

        // --- p = exp(s-16), masked -> 0 ---
        const unsigned long long bits = padbits[b * 64 + t];
        #pragma unroll
        for (int tl = 0; tl < 4; ++tl) {
            const bool pad = (bits >> (tl * 16 + fr)) & 1ull;
            const int col = kv0 + tl * 16 + fr;
            #pragma unroll
            for (int r = 0; r < 4; ++r) {
                float p = __expf(sc[tl][r] - 16.0f);
                bool msk = pad || (causal && (col > (qw + fq * 4 + r)));
                sc[tl][r] = msk ? 0.f : p;
            }
        }

        // --- P -> per-wave LDS (bf16, swizzled) for operand transpose ---
        #pragma unroll
        for (int tl = 0; tl < 4; ++tl) {
            #pragma unroll
            for (int r = 0; r < 4; ++r) {
                int prow = fq * 4 + r;
                int pcb = (tl * 16 + fr) * 2;
                *(unsigned short*)(Pw + prow * 128 + (pcb ^ ((prow & 7) << 4))) = f2bf(sc[tl][r]);
            }
        }

        if (i + 1 < tcnt) LOADK(kv0 + 64);     // K[t+1] loads overlap PV

        asm volatile("s_waitcnt lgkmcnt(0)" ::: "memory");
        __builtin_amdgcn_sched_barrier(0);

        // --- PV + row-sum via ones-MFMA ---
        s16x8 pa0 = *(const s16x8*)(Pw + fr * 128 + ((fq * 16) ^ ((fr & 7) << 4)));
        s16x8 pa1 = *(const s16x8*)(Pw + fr * 128 + ((64 + fq * 16) ^ ((fr & 7) << 4)));
        lacc = __builtin_amdgcn_mfma_f32_16x16x32_bf16(pa0, onesb, lacc, 0, 0, 0);
        lacc = __builtin_amdgcn_mfma_f32_16x16x32_bf16(pa1, onesb, lacc, 0, 0, 0);
        #pragma unroll
        for (int dt = 0; dt < 4; ++dt) {
            Oa[dt] = __builtin_amdgcn_mfma_f32_16x16x32_bf16(pa0, vf[dt][0], Oa[dt], 0, 0, 0);
            Oa[dt] = __builtin_amdgcn_mfma_f32_16x16x32_bf16(pa1, vf[dt][1], Oa[dt], 0, 0, 0);
        }
        // P buffer is wave-private; lgkmcnt(0) above orders this tile's
        // reads before next tile's writes (same wave) -- no barrier needed.
    }

    if (qt < 8) {
        // --- single chunk: final output directly (fp32) ---
        #pragma unroll
        for (int r = 0; r < 4; ++r) {
            int qrow = qw + fq * 4 + r;
            float l = lacc[r];
            bool dead = !(l > 0.f);
            float inv = dead ? 0.f : 1.0f / l;
            #pragma unroll
            for (int dt = 0; dt < 4; ++dt) {
                int d = dt * 16 + fr;
                float val = dead ? meanVsum[b * 64 + d] * (1.0f / (float)Sn)
                                 : Oa[dt][r] * inv;
                out[((size_t)(b * Sn + qrow)) * 64 + d] = val;
            }
        }
    } else {
        // --- partial: normalized O/l (bf16) + l ---
        const int slot = (b * 64 + qt) * 8 + c;
        #pragma unroll
        for (int r = 0; r < 4; ++r) {
            int row16 = w * 16 + fq * 4 + r;
            float l = lacc[r];
            float inv = (l > 0.f) ? 1.0f / l : 0.f;
            #pragma unroll
            for (int dt = 0; dt < 4; ++dt)
                Onorm[slot * 4096 + row16 * 64 + dt * 16 + fr] = f2bf(Oa[dt][r] * inv);
            if (fr == 0) Lp[slot * 64 + row16] = l;
        }
    }
}

// ---------------------------------------------------------------------------
// Kernel 4: combine partials for qt >= 8 only.  Weights are just l_c.
// Dead row (sum l == 0): reference softmax uniform over ALL S -> meanV.
// ---------------------------------------------------------------------------
__global__ void LPSAN_combine_kernel(
    const unsigned short* __restrict__ Onorm, const float* __restrict__ Lp,
    const float* __restrict__ meanVsum, float* __restrict__ out)
{
    const int qt = 8 + blockIdx.x, b = blockIdx.y;
    const int nch = (qt >> 3) + 1;
    const int t = threadIdx.x;
    const int row = t >> 2, q4 = t & 3;
    const int slotbase = (b * 64 + qt) * 8;

    float wsum = 0.f, wgt[8];
    for (int c = 0; c < nch; ++c) { wgt[c] = Lp[(slotbase + c) * 64 + row]; wsum += wgt[c]; }
    const bool dead = !(wsum > 0.f);

    float acc[16];
    #pragma unroll
    for (int j = 0; j < 16; ++j) acc[j] = 0.f;
    for (int c = 0; c < nch; ++c) {
        const unsigned short* src = Onorm + (slotbase + c) * 4096 + row * 64 + q4 * 16;
        u16x8 a0 = *(const u16x8*)(src);
        u16x8 a1 = *(const u16x8*)(src + 8);
        #pragma unroll
        for (int j = 0; j < 8; ++j) { acc[j] += wgt[c] * bf2f(a0[j]); acc[j + 8] += wgt[c] * bf2f(a1[j]); }
    }

    const float inv = dead ? 0.f : 1.0f / wsum;
    float4 o[4];
    #pragma unroll
    for (int v = 0; v < 4; ++v) {
        #pragma unroll
        for (int j = 0; j < 4; ++j) {
            int d = q4 * 16 + v * 4 + j;
            float val = dead ? meanVsum[b * 64 + d] * (1.0f / (float)Sn) : acc[v * 4 + j] * inv;
            ((float*)&o[v])[j] = val;
        }
    }
    float* dst = out + ((size_t)(b * Sn + qt * 64 + row) * 64 + q4 * 16);
    #pragma unroll
    for (int v = 0; v < 4; ++v) *(float4*)(dst + v * 4) = o[v];
}

// ---------------------------------------------------------------------------
extern "C" void kernel_launch(void* const* d_in, const int* in_sizes, int n_in,
                              void* d_out, int out_size, void* d_ws, size_t ws_size,
                              hipStream_t stream) {
    const float* E  = (const float*)d_in[0];
    const float* PK = (const float*)d_in[1];
    const float* PV = (const float*)d_in[2];
    const float* Wq = (const float*)d_in[3];
    const float* bq = (const float*)d_in[4];
    const float* Wk = (const float*)d_in[5];
    const float* bk = (const float*)d_in[6];
    const float* Wv = (const float*)d_in[7];
    const float* bv = (const float*)d_in[8];
    const unsigned char* pm = (const unsigned char*)d_in[9];

    char* ws = (char*)d_ws;
    const size_t SZ = (size_t)Bn * Sn * Dn * sizeof(unsigned short);   // 2 MB each
    unsigned short* Qb = (unsigned short*)(ws);
    unsigned short* Kb = (unsigned short*)(ws + SZ);
    unsigned short* Vt = (unsigned short*)(ws + 2 * SZ);
    unsigned short* On = (unsigned short*)(ws + 3 * SZ);               // 16 MB
    const size_t ONB = (size_t)Bn * 64 * 8 * 4096 * sizeof(unsigned short);
    float* Lp = (float*)(ws + 3 * SZ + ONB);                           // 512 KB
    unsigned long long* padbits = (unsigned long long*)(ws + 3 * SZ + ONB + 524288);
    float* meanVsum = (float*)(ws + 3 * SZ + ONB + 524288 + 4096);
    float* out = (float*)d_out;

    hipLaunchKernelGGL(LPSAN_init_kernel, dim3(9), dim3(256), 0, stream, pm, padbits, meanVsum);
    hipLaunchKernelGGL(LPSAN_proj_kernel, dim3(Bn * Sn / 64), dim3(256), 0, stream,
                       E, PK, PV, Wq, bq, Wk, bk, Wv, bv, Qb, Kb, Vt, meanVsum);
    hipLaunchKernelGGL(LPSAN_attn_kernel, dim3(288, Bn), dim3(256), 0, stream,
                       Qb, Kb, Vt, padbits, meanVsum, On, Lp, out);
    hipLaunchKernelGGL(LPSAN_combine_kernel, dim3(56, Bn), dim3(256), 0, stream,
                       On, Lp, meanVsum, out);
}

// Round 7
// 172.337 us; speedup vs baseline: 1.1785x; 1.1785x over previous
//
#include <hip/hip_runtime.h>
#include <hip/hip_bf16.h>

#define Bn 4
#define Sn 4096
#define Dn 64

typedef short          s16x8 __attribute__((ext_vector_type(8)));
typedef unsigned short u16x8 __attribute__((ext_vector_type(8)));
typedef float          f32x4 __attribute__((ext_vector_type(4)));

__device__ __forceinline__ unsigned short f2bf(float f) {
    unsigned u = __float_as_uint(f);
    u = u + 0x7fffu + ((u >> 16) & 1u);   // RNE
    return (unsigned short)(u >> 16);
}
__device__ __forceinline__ float bf2f(unsigned short h) {
    return __uint_as_float(((unsigned)h) << 16);
}
__device__ __forceinline__ unsigned long long pack4(float4 x) {
    return (unsigned long long)f2bf(x.x)
         | ((unsigned long long)f2bf(x.y) << 16)
         | ((unsigned long long)f2bf(x.z) << 32)
         | ((unsigned long long)f2bf(x.w) << 48);
}

// ---------------------------------------------------------------------------
// Kernel 1 (init): 9 blocks x 256 threads.
//   blocks 0..7 : pack pad_mask into padbits (32 words of 64 cols each).
//                 dtype detection (uint8 vs int32 bool storage) per block,
//                 window restricted to the first 16KB (safe in both interps).
//   block 8     : zero meanVsum (256 floats)  [replaces hipMemsetAsync].
// ---------------------------------------------------------------------------
__global__ void LPSAN_init_kernel(const unsigned char* pm, unsigned long long* padbits,
                                  float* meanVsum) {
    const int k = blockIdx.x, t = threadIdx.x;
    if (k == 8) { meanVsum[t] = 0.f; return; }

    __shared__ unsigned nzs;
    if (t == 0) nzs = 0u;
    __syncthreads();
    { // detection: bytes [k*2048, (k+1)*2048) -- inside first 16KB, safe always
        const uint2* p2 = (const uint2*)(pm + k * 2048);
        uint2 x = p2[t];
        unsigned acc = (x.x & 0xFFFFFF00u) | (x.y & 0xFFFFFF00u);
        if (acc) atomicOr(&nzs, 1u);
    }
    __syncthreads();
    if (t >= 32) return;
    const int wi = k * 32 + t;              // padbits word index
    unsigned long long bits = 0ull;
    if (nzs) {                              // uint8 storage: 64 bytes
        const uint4* p4 = (const uint4*)(pm + wi * 64);
        #pragma unroll
        for (int q = 0; q < 4; ++q) {
            uint4 x = p4[q];
            unsigned w[4] = { x.x, x.y, x.z, x.w };
            #pragma unroll
            for (int wj = 0; wj < 4; ++wj)
                #pragma unroll
                for (int bb = 0; bb < 4; ++bb)
                    bits |= (unsigned long long)(((w[wj] >> (8 * bb)) & 0xFFu) != 0u)
                            << (q * 16 + wj * 4 + bb);
        }
    } else {                                // int32 storage: 64 ints
        const uint4* p4 = (const uint4*)pm + wi * 16;
        #pragma unroll
        for (int q = 0; q < 16; ++q) {
            uint4 x = p4[q];
            bits |= (unsigned long long)(x.x != 0u) << (q * 4);
            bits |= (unsigned long long)(x.y != 0u) << (q * 4 + 1);
            bits |= (unsigned long long)(x.z != 0u) << (q * 4 + 2);
            bits |= (unsigned long long)(x.w != 0u) << (q * 4 + 3);
        }
    }
    padbits[wi] = bits;
}

// ---------------------------------------------------------------------------
// Kernel 2: MFMA QKV projection.  64 rows/block, 256 blocks, 4 waves x 16
// rows.  E and W staged as bf16 in LDS with XOR swizzle ^((row&7)<<4); 8
// MFMA (16x16x32) per matrix per wave.  Epilogue: bias+modulation in fp32,
// routed through a padded LDS buffer for coalesced 16B global stores.
//   Qb = (E@Wq^T+bq)*0.125 ; Kb = (.)*P_K ; Vt[b][d][s] = (.)*P_V (transposed)
// Also accumulates meanVsum[b*64+d] = sum_s V_p.
// ---------------------------------------------------------------------------
__global__ void LPSAN_proj_kernel(
    const float* __restrict__ E, const float* __restrict__ PK, const float* __restrict__ PV,
    const float* __restrict__ Wq, const float* __restrict__ bq,
    const float* __restrict__ Wk, const float* __restrict__ bk,
    const float* __restrict__ Wv, const float* __restrict__ bv,
    unsigned short* __restrict__ Qb, unsigned short* __restrict__ Kb,
    unsigned short* __restrict__ Vt, float* __restrict__ meanVsum)
{
    __shared__ unsigned short Ebf[4096];        // [64][64] bf16, swizzled (8KB)
    __shared__ unsigned short Wbf[3][4096];     // swizzled (24KB)
    __shared__ unsigned short Tbuf[64 * 72];    // 144B rows, transpose staging (9KB)

    const int t = threadIdx.x;                  // 256 threads
    const int r0 = blockIdx.x * 64;
    const int b  = r0 >> 12;
    const int s0 = r0 & (Sn - 1);
    const int w = t >> 6, lane = t & 63;
    const int fq = lane >> 4, fr = lane & 15;

    { // stage E and W: fp32 -> bf16, swizzled 8B writes
        const float4* Eg = (const float4*)(E + (size_t)r0 * 64);
        #pragma unroll
        for (int v = 0; v < 4; ++v) {
            int f = t + v * 256;
            float4 x = Eg[f];
            int row = f >> 4, c4 = f & 15;
            *(unsigned long long*)((char*)Ebf + row * 128 + ((c4 * 8) ^ ((row & 7) << 4))) = pack4(x);
        }
        #pragma unroll
        for (int m = 0; m < 3; ++m) {
            const float4* Wg = (const float4*)(m == 0 ? Wq : m == 1 ? Wk : Wv);
            #pragma unroll
            for (int v = 0; v < 4; ++v) {
                int f = t + v * 256;
                float4 x = Wg[f];
                int row = f >> 4, c4 = f & 15;
                *(unsigned long long*)((char*)Wbf[m] + row * 128 + ((c4 * 8) ^ ((row & 7) << 4))) = pack4(x);
            }
        }
    }
    __syncthreads();

    // A-frags: E[row = w*16+fr][k = ks*32 + fq*8+i]
    const int  arow = w * 16 + fr;
    const int  swz  = (fr & 7) << 4;            // (arow&7) == (fr&7) == (ct*16+fr)&7
    const char* Ec = (const char*)Ebf;
    const s16x8 ea0 = *(const s16x8*)(Ec + arow * 128 + ((fq * 16) ^ swz));
    const s16x8 ea1 = *(const s16x8*)(Ec + arow * 128 + ((64 + fq * 16) ^ swz));

    const int sl0 = w * 16 + fq * 4;            // lane's first local output row

    for (int m = 0; m < 3; ++m) {
        const char*  Wc   = (const char*)Wbf[m];
        const float* bias = (m == 0) ? bq : (m == 1) ? bk : bv;

        f32x4 acc[4];
        #pragma unroll
        for (int ct = 0; ct < 4; ++ct) {        // B-frag: W[j=ct*16+fr][k=fq*8+i]
            const int brow = ct * 16 + fr;
            s16x8 b0 = *(const s16x8*)(Wc + brow * 128 + ((fq * 16) ^ swz));
            s16x8 b1 = *(const s16x8*)(Wc + brow * 128 + ((64 + fq * 16) ^ swz));
            f32x4 z = f32x4{0.f, 0.f, 0.f, 0.f};
            z = __builtin_amdgcn_mfma_f32_16x16x32_bf16(ea0, b0, z, 0, 0, 0);
            z = __builtin_amdgcn_mfma_f32_16x16x32_bf16(ea1, b1, z, 0, 0, 0);
            acc[ct] = z;
        }

        if (m < 2) {                            // Q / K: Tbuf as [s][j]
            #pragma unroll
            for (int ct = 0; ct < 4; ++ct) {
                const int j = ct * 16 + fr;
                const float bb = bias[j];
                if (m == 0) {
                    #pragma unroll
                    for (int r = 0; r < 4; ++r)
                        Tbuf[(sl0 + r) * 72 + j] = f2bf((acc[ct][r] + bb) * 0.125f);
                } else {
                    #pragma unroll
                    for (int r = 0; r < 4; ++r) {
                        float mod = PK[(size_t)(r0 + sl0 + r) * 64 + j];
                        Tbuf[(sl0 + r) * 72 + j] = f2bf((acc[ct][r] + bb) * mod);
                    }
                }
            }
            __syncthreads();
            { // coalesced read-back + 16B global stores
                unsigned short* dst = (m == 0 ? Qb : Kb)
                    + (size_t)(b * Sn + s0 + (t >> 2)) * 64 + (t & 3) * 16;
                u16x8 o0 = *(const u16x8*)&Tbuf[(t >> 2) * 72 + (t & 3) * 16];
                u16x8 o1 = *(const u16x8*)&Tbuf[(t >> 2) * 72 + (t & 3) * 16 + 8];
                *(u16x8*)dst = o0;
                *(u16x8*)(dst + 8) = o1;
            }
            __syncthreads();
        } else {                                // V: Tbuf as [d][s], packed b64 writes
            #pragma unroll
            for (int ct = 0; ct < 4; ++ct) {
                const int j = ct * 16 + fr;
                const float bb = bias[j];
                unsigned long long pk = 0;
                #pragma unroll
                for (int r = 0; r < 4; ++r) {
                    float mod = PV[(size_t)(r0 + sl0 + r) * 64 + j];
                    pk |= (unsigned long long)f2bf((acc[ct][r] + bb) * mod) << (16 * r);
                }
                *(unsigned long long*)&Tbuf[j * 72 + sl0] = pk;
            }
            __syncthreads();
            {
                const int d = t >> 2, seg = t & 3;
                u16x8 o0 = *(const u16x8*)&Tbuf[d * 72 + seg * 16];
                u16x8 o1 = *(const u16x8*)&Tbuf[d * 72 + seg * 16 + 8];
                unsigned short* dst = Vt + (size_t)(b * 64 + d) * Sn + s0 + seg * 16;
                *(u16x8*)dst = o0;
                *(u16x8*)(dst + 8) = o1;
                float s = 0.f;
                #pragma unroll
                for (int i = 0; i < 8; ++i) s += bf2f(o0[i]) + bf2f(o1[i]);
                s += __shfl_xor(s, 1);
                s += __shfl_xor(s, 2);
                if ((t & 3) == 0) atomicAdd(&meanVsum[b * 64 + d], s);
            }
        }
    }
}

// ---------------------------------------------------------------------------
// Kernel 3: flash attention, split-KV, BARRIER-FREE.
// K/V are L2-resident (2MB each) -> no LDS staging: each wave loads its MFMA
// B-fragments directly from global (16B/lane; 64B-contiguous per row).
// No __syncthreads / vmcnt(0) stalls; the 4 waves per block run free.
// Only LDS: per-wave 2KB swizzled P-transpose buffer.
// __launch_bounds__(256,2): VGPR cap 256 -- round-6's (256,4) capped VGPRs
// at 64 and spilled ~24MB/dispatch to scratch (WRITE_SIZE 9.8->33.9MB).
// Static-offset softmax p = exp(s-16); row-sum l via all-ones-B MFMA.
// Block = (b, qt, chunk of <=8 KV tiles), grid (288, 4), longest first.
// ---------------------------------------------------------------------------
__global__ __launch_bounds__(256, 2) void LPSAN_attn_kernel(
    const unsigned short* __restrict__ Qb, const unsigned short* __restrict__ Kb,
    const unsigned short* __restrict__ Vt, const unsigned long long* __restrict__ padbits,
    const float* __restrict__ meanVsum,
    unsigned short* __restrict__ Onorm, float* __restrict__ Lp, float* __restrict__ out)
{
    __shared__ unsigned short Plds[4][1024];   // per-wave P 16x64 swizzled (8KB)

    // --- map reversed blockIdx.x -> (qt, c); longest chunks first ---
    int id = 287 - blockIdx.x, g = 0, base = 0;
    while (id >= base + 8 * (g + 1)) { base += 8 * (g + 1); ++g; }
    const int rel = id - base;
    const int qt = 8 * g + rel / (g + 1);
    const int c  = rel % (g + 1);

    const int b = blockIdx.y;
    const int q0 = qt * 64;
    const int t0 = c * 8;
    const int tcnt = min(8, qt + 1 - t0);
    const int tid = threadIdx.x;
    const int w = tid >> 6, lane = tid & 63;
    const int fq = lane >> 4, fr = lane & 15;
    const int qw = q0 + w * 16;

    // per-lane row bases for direct B-frag loads
    const unsigned short* Kln = Kb + b * (Sn * Dn) + fr * 64 + fq * 8;   // + kvrow*64 (+32)
    const unsigned short* Vln = Vt + b * (Dn * Sn) + fr * Sn + fq * 8;   // + d0*Sn + kv0 (+32)

    const s16x8 qf0 = *(const s16x8*)(Qb + (b * Sn + qw + fr) * 64 + fq * 8);
    const s16x8 qf1 = *(const s16x8*)(Qb + (b * Sn + qw + fr) * 64 + 32 + fq * 8);

    s16x8 onesb;                               // all-ones bf16 B operand
    #pragma unroll
    for (int i = 0; i < 8; ++i) onesb[i] = (short)0x3F80;

    f32x4 Oa[4];
    f32x4 lacc = f32x4{0.f, 0.f, 0.f, 0.f};
    #pragma unroll
    for (int i = 0; i < 4; ++i) Oa[i] = f32x4{0.f, 0.f, 0.f, 0.f};

    char* Pw = (char*)&Plds[w][0];

    s16x8 kf[4][2], vf[4][2];

    auto LOADK = [&](int kv0) {
        #pragma unroll
        for (int tl = 0; tl < 4; ++tl) {
            const unsigned short* p = Kln + (kv0 + tl * 16) * 64;
            kf[tl][0] = *(const s16x8*)(p);
            kf[tl][1] = *(const s16x8*)(p + 32);
        }
    };
    auto LOADV = [&](int kv0) {
        #pragma unroll
        for (int dt = 0; dt < 4; ++dt) {
            const unsigned short* p = Vln + (dt * 16) * Sn + kv0;
            vf[dt][0] = *(const s16x8*)(p);
            vf[dt][1] = *(const s16x8*)(p + 32);
        }
    };

    LOADK(t0 * 64);
    for (int i = 0; i < tcnt; ++i) {
        const int t = t0 + i;
        const int kv0 = t * 64;
        const bool causal = (t == qt);

        LOADV(kv0);                            // V loads overlap QK + exp

        // --- scores: Q (16x64) x K_p^T -> 4 col-tiles of 16 ---
        f32x4 sc[4];
        #pragma unroll
        for (int tl = 0; tl < 4; ++tl) {
            f32x4 z = f32x4{0.f, 0.f, 0.f, 0.f};
            z = __builtin_amdgcn_mfma_f32_16x16x32_bf16(qf0, kf[tl][0], z, 0, 0, 0);
            z = __builtin_amdgcn_mfma_f32_16x16x32_bf16(qf1, kf[tl][1], z, 0, 0, 0);
            sc[tl] = z;
        }

        // --- p = exp(s-16), masked -> 0 ---
        const unsigned long long bits = padbits[b * 64 + t];
        #pragma unroll
        for (int tl = 0; tl < 4; ++tl) {
            const bool pad = (bits >> (tl * 16 + fr)) & 1ull;
            const int col = kv0 + tl * 16 + fr;
            #pragma unroll
            for (int r = 0; r < 4; ++r) {
                float p = __expf(sc[tl][r] - 16.0f);
                bool msk = pad || (causal && (col > (qw + fq * 4 + r)));
                sc[tl][r] = msk ? 0.f : p;
            }
        }

        // --- P -> per-wave LDS (bf16, swizzled) for operand transpose ---
        #pragma unroll
        for (int tl = 0; tl < 4; ++tl) {
            #pragma unroll
            for (int r = 0; r < 4; ++r) {
                int prow = fq * 4 + r;
                int pcb = (tl * 16 + fr) * 2;
                *(unsigned short*)(Pw + prow * 128 + (pcb ^ ((prow & 7) << 4))) = f2bf(sc[tl][r]);
            }
        }

        if (i + 1 < tcnt) LOADK(kv0 + 64);     // K[t+1] loads overlap PV

        asm volatile("s_waitcnt lgkmcnt(0)" ::: "memory");
        __builtin_amdgcn_sched_barrier(0);

        // --- PV + row-sum via ones-MFMA ---
        s16x8 pa0 = *(const s16x8*)(Pw + fr * 128 + ((fq * 16) ^ ((fr & 7) << 4)));
        s16x8 pa1 = *(const s16x8*)(Pw + fr * 128 + ((64 + fq * 16) ^ ((fr & 7) << 4)));
        lacc = __builtin_amdgcn_mfma_f32_16x16x32_bf16(pa0, onesb, lacc, 0, 0, 0);
        lacc = __builtin_amdgcn_mfma_f32_16x16x32_bf16(pa1, onesb, lacc, 0, 0, 0);
        #pragma unroll
        for (int dt = 0; dt < 4; ++dt) {
            Oa[dt] = __builtin_amdgcn_mfma_f32_16x16x32_bf16(pa0, vf[dt][0], Oa[dt], 0, 0, 0);
            Oa[dt] = __builtin_amdgcn_mfma_f32_16x16x32_bf16(pa1, vf[dt][1], Oa[dt], 0, 0, 0);
        }
        // P buffer is wave-private; lgkmcnt(0) above orders this tile's
        // reads before next tile's writes (same wave) -- no barrier needed.
    }

    if (qt < 8) {
        // --- single chunk: final output directly (fp32) ---
        #pragma unroll
        for (int r = 0; r < 4; ++r) {
            int qrow = qw + fq * 4 + r;
            float l = lacc[r];
            bool dead = !(l > 0.f);
            float inv = dead ? 0.f : 1.0f / l;
            #pragma unroll
            for (int dt = 0; dt < 4; ++dt) {
                int d = dt * 16 + fr;
                float val = dead ? meanVsum[b * 64 + d] * (1.0f / (float)Sn)
                                 : Oa[dt][r] * inv;
                out[((size_t)(b * Sn + qrow)) * 64 + d] = val;
            }
        }
    } else {
        // --- partial: normalized O/l (bf16) + l ---
        const int slot = (b * 64 + qt) * 8 + c;
        #pragma unroll
        for (int r = 0; r < 4; ++r) {
            int row16 = w * 16 + fq * 4 + r;
            float l = lacc[r];
            float inv = (l > 0.f) ? 1.0f / l : 0.f;
            #pragma unroll
            for (int dt = 0; dt < 4; ++dt)
                Onorm[slot * 4096 + row16 * 64 + dt * 16 + fr] = f2bf(Oa[dt][r] * inv);
            if (fr == 0) Lp[slot * 64 + row16] = l;
        }
    }
}

// ---------------------------------------------------------------------------
// Kernel 4: combine partials for qt >= 8 only.  Weights are just l_c.
// Dead row (sum l == 0): reference softmax uniform over ALL S -> meanV.
// ---------------------------------------------------------------------------
__global__ void LPSAN_combine_kernel(
    const unsigned short* __restrict__ Onorm, const float* __restrict__ Lp,
    const float* __restrict__ meanVsum, float* __restrict__ out)
{
    const int qt = 8 + blockIdx.x, b = blockIdx.y;
    const int nch = (qt >> 3) + 1;
    const int t = threadIdx.x;
    const int row = t >> 2, q4 = t & 3;
    const int slotbase = (b * 64 + qt) * 8;

    float wsum = 0.f, wgt[8];
    for (int c = 0; c < nch; ++c) { wgt[c] = Lp[(slotbase + c) * 64 + row]; wsum += wgt[c]; }
    const bool dead = !(wsum > 0.f);

    float acc[16];
    #pragma unroll
    for (int j = 0; j < 16; ++j) acc[j] = 0.f;
    for (int c = 0; c < nch; ++c) {
        const unsigned short* src = Onorm + (slotbase + c) * 4096 + row * 64 + q4 * 16;
        u16x8 a0 = *(const u16x8*)(src);
        u16x8 a1 = *(const u16x8*)(src + 8);
        #pragma unroll
        for (int j = 0; j < 8; ++j) { acc[j] += wgt[c] * bf2f(a0[j]); acc[j + 8] += wgt[c] * bf2f(a1[j]); }
    }

    const float inv = dead ? 0.f : 1.0f / wsum;
    float4 o[4];
    #pragma unroll
    for (int v = 0; v < 4; ++v) {
        #pragma unroll
        for (int j = 0; j < 4; ++j) {
            int d = q4 * 16 + v * 4 + j;
            float val = dead ? meanVsum[b * 64 + d] * (1.0f / (float)Sn) : acc[v * 4 + j] * inv;
            ((float*)&o[v])[j] = val;
        }
    }
    float* dst = out + ((size_t)(b * Sn + qt * 64 + row) * 64 + q4 * 16);
    #pragma unroll
    for (int v = 0; v < 4; ++v) *(float4*)(dst + v * 4) = o[v];
}

// ---------------------------------------------------------------------------
extern "C" void kernel_launch(void* const* d_in, const int* in_sizes, int n_in,
                              void* d_out, int out_size, void* d_ws, size_t ws_size,
                              hipStream_t stream) {
    const float* E  = (const float*)d_in[0];
    const float* PK = (const float*)d_in[1];
    const float* PV = (const float*)d_in[2];
    const float* Wq = (const float*)d_in[3];
    const float* bq = (const float*)d_in[4];
    const float* Wk = (const float*)d_in[5];
    const float* bk = (const float*)d_in[6];
    const float* Wv = (const float*)d_in[7];
    const float* bv = (const float*)d_in[8];
    const unsigned char* pm = (const unsigned char*)d_in[9];

    char* ws = (char*)d_ws;
    const size_t SZ = (size_t)Bn * Sn * Dn * sizeof(unsigned short);   // 2 MB each
    unsigned short* Qb = (unsigned short*)(ws);
    unsigned short* Kb = (unsigned short*)(ws + SZ);
    unsigned short* Vt = (unsigned short*)(ws + 2 * SZ);
    unsigned short* On = (unsigned short*)(ws + 3 * SZ);               // 16 MB
    const size_t ONB = (size_t)Bn * 64 * 8 * 4096 * sizeof(unsigned short);
    float* Lp = (float*)(ws + 3 * SZ + ONB);                           // 512 KB
    unsigned long long* padbits = (unsigned long long*)(ws + 3 * SZ + ONB + 524288);
    float* meanVsum = (float*)(ws + 3 * SZ + ONB + 524288 + 4096);
    float* out = (float*)d_out;

    hipLaunchKernelGGL(LPSAN_init_kernel, dim3(9), dim3(256), 0, stream, pm, padbits, meanVsum);
    hipLaunchKernelGGL(LPSAN_proj_kernel, dim3(Bn * Sn / 64), dim3(256), 0, stream,
                       E, PK, PV, Wq, bq, Wk, bk, Wv, bv, Qb, Kb, Vt, meanVsum);
    hipLaunchKernelGGL(LPSAN_attn_kernel, dim3(288, Bn), dim3(256), 0, stream,
                       Qb, Kb, Vt, padbits, meanVsum, On, Lp, out);
    hipLaunchKernelGGL(LPSAN_combine_kernel, dim3(56, Bn), dim3(256), 0, stream,
                       On, Lp, meanVsum, out);
}

// Round 8
// 138.235 us; speedup vs baseline: 1.4692x; 1.2467x over previous
//
#include <hip/hip_runtime.h>
#include <hip/hip_bf16.h>

#define Bn 4
#define Sn 4096
#define Dn 64

typedef short          s16x8 __attribute__((ext_vector_type(8)));
typedef unsigned short u16x8 __attribute__((ext_vector_type(8)));
typedef float          f32x4 __attribute__((ext_vector_type(4)));

typedef __attribute__((address_space(1))) const void gas_void;
typedef __attribute__((address_space(3))) void       las_void;

__device__ __forceinline__ unsigned short f2bf(float f) {
    unsigned u = __float_as_uint(f);
    u = u + 0x7fffu + ((u >> 16) & 1u);   // RNE
    return (unsigned short)(u >> 16);
}
__device__ __forceinline__ float bf2f(unsigned short h) {
    return __uint_as_float(((unsigned)h) << 16);
}
__device__ __forceinline__ unsigned long long pack4(float4 x) {
    return (unsigned long long)f2bf(x.x)
         | ((unsigned long long)f2bf(x.y) << 16)
         | ((unsigned long long)f2bf(x.z) << 32)
         | ((unsigned long long)f2bf(x.w) << 48);
}
__device__ __forceinline__ void gld16(const void* g, void* l) {
    __builtin_amdgcn_global_load_lds((gas_void*)g, (las_void*)l, 16, 0, 0);
}

// ---------------------------------------------------------------------------
// Kernel 1 (init): 9 blocks x 256 threads.
//   blocks 0..7 : pack pad_mask into padbits (32 words of 64 cols each).
//                 dtype detection (uint8 vs int32 bool storage) per block,
//                 window restricted to the first 16KB (safe in both interps).
//   block 8     : zero meanVsum (256 floats)  [replaces hipMemsetAsync].
// ---------------------------------------------------------------------------
__global__ void LPSAN_init_kernel(const unsigned char* pm, unsigned long long* padbits,
                                  float* meanVsum) {
    const int k = blockIdx.x, t = threadIdx.x;
    if (k == 8) { meanVsum[t] = 0.f; return; }

    __shared__ unsigned nzs;
    if (t == 0) nzs = 0u;
    __syncthreads();
    { // detection: bytes [k*2048, (k+1)*2048) -- inside first 16KB, safe always
        const uint2* p2 = (const uint2*)(pm + k * 2048);
        uint2 x = p2[t];
        unsigned acc = (x.x & 0xFFFFFF00u) | (x.y & 0xFFFFFF00u);
        if (acc) atomicOr(&nzs, 1u);
    }
    __syncthreads();
    if (t >= 32) return;
    const int wi = k * 32 + t;              // padbits word index
    unsigned long long bits = 0ull;
    if (nzs) {                              // uint8 storage: 64 bytes
        const uint4* p4 = (const uint4*)(pm + wi * 64);
        #pragma unroll
        for (int q = 0; q < 4; ++q) {
            uint4 x = p4[q];
            unsigned w[4] = { x.x, x.y, x.z, x.w };
            #pragma unroll
            for (int wj = 0; wj < 4; ++wj)
                #pragma unroll
                for (int bb = 0; bb < 4; ++bb)
                    bits |= (unsigned long long)(((w[wj] >> (8 * bb)) & 0xFFu) != 0u)
                            << (q * 16 + wj * 4 + bb);
        }
    } else {                                // int32 storage: 64 ints
        const uint4* p4 = (const uint4*)pm + wi * 16;
        #pragma unroll
        for (int q = 0; q < 16; ++q) {
            uint4 x = p4[q];
            bits |= (unsigned long long)(x.x != 0u) << (q * 4);
            bits |= (unsigned long long)(x.y != 0u) << (q * 4 + 1);
            bits |= (unsigned long long)(x.z != 0u) << (q * 4 + 2);
            bits |= (unsigned long long)(x.w != 0u) << (q * 4 + 3);
        }
    }
    padbits[wi] = bits;
}

// ---------------------------------------------------------------------------
// Kernel 2: MFMA QKV projection.  64 rows/block, 256 blocks, 4 waves x 16
// rows.  E and W staged as bf16 in LDS with XOR swizzle ^((row&7)<<4); 8
// MFMA (16x16x32) per matrix per wave.  Epilogue: bias+modulation in fp32,
// routed through a padded LDS buffer for coalesced 16B global stores.
//   Qb = (E@Wq^T+bq)*0.125 ; Kb = (.)*P_K ; Vt[b][d][s] = (.)*P_V (transposed)
// Also accumulates meanVsum[b*64+d] = sum_s V_p.
// ---------------------------------------------------------------------------
__global__ void LPSAN_proj_kernel(
    const float* __restrict__ E, const float* __restrict__ PK, const float* __restrict__ PV,
    const float* __restrict__ Wq, const float* __restrict__ bq,
    const float* __restrict__ Wk, const float* __restrict__ bk,
    const float* __restrict__ Wv, const float* __restrict__ bv,
    unsigned short* __restrict__ Qb, unsigned short* __restrict__ Kb,
    unsigned short* __restrict__ Vt, float* __restrict__ meanVsum)
{
    __shared__ unsigned short Ebf[4096];        // [64][64] bf16, swizzled (8KB)
    __shared__ unsigned short Wbf[3][4096];     // swizzled (24KB)
    __shared__ unsigned short Tbuf[64 * 72];    // 144B rows, transpose staging (9KB)

    const int t = threadIdx.x;                  // 256 threads
    const int r0 = blockIdx.x * 64;
    const int b  = r0 >> 12;
    const int s0 = r0 & (Sn - 1);
    const int w = t >> 6, lane = t & 63;
    const int fq = lane >> 4, fr = lane & 15;

    { // stage E and W: fp32 -> bf16, swizzled 8B writes
        const float4* Eg = (const float4*)(E + (size_t)r0 * 64);
        #pragma unroll
        for (int v = 0; v < 4; ++v) {
            int f = t + v * 256;
            float4 x = Eg[f];
            int row = f >> 4, c4 = f & 15;
            *(unsigned long long*)((char*)Ebf + row * 128 + ((c4 * 8) ^ ((row & 7) << 4))) = pack4(x);
        }
        #pragma unroll
        for (int m = 0; m < 3; ++m) {
            const float4* Wg = (const float4*)(m == 0 ? Wq : m == 1 ? Wk : Wv);
            #pragma unroll
            for (int v = 0; v < 4; ++v) {
                int f = t + v * 256;
                float4 x = Wg[f];
                int row = f >> 4, c4 = f & 15;
                *(unsigned long long*)((char*)Wbf[m] + row * 128 + ((c4 * 8) ^ ((row & 7) << 4))) = pack4(x);
            }
        }
    }
    __syncthreads();

    // A-frags: E[row = w*16+fr][k = ks*32 + fq*8+i]
    const int  arow = w * 16 + fr;
    const int  swz  = (fr & 7) << 4;            // (arow&7) == (fr&7) == (ct*16+fr)&7
    const char* Ec = (const char*)Ebf;
    const s16x8 ea0 = *(const s16x8*)(Ec + arow * 128 + ((fq * 16) ^ swz));
    const s16x8 ea1 = *(const s16x8*)(Ec + arow * 128 + ((64 + fq * 16) ^ swz));

    const int sl0 = w * 16 + fq * 4;            // lane's first local output row

    for (int m = 0; m < 3; ++m) {
        const char*  Wc   = (const char*)Wbf[m];
        const float* bias = (m == 0) ? bq : (m == 1) ? bk : bv;

        f32x4 acc[4];
        #pragma unroll
        for (int ct = 0; ct < 4; ++ct) {        // B-frag: W[j=ct*16+fr][k=fq*8+i]
            const int brow = ct * 16 + fr;
            s16x8 b0 = *(const s16x8*)(Wc + brow * 128 + ((fq * 16) ^ swz));
            s16x8 b1 = *(const s16x8*)(Wc + brow * 128 + ((64 + fq * 16) ^ swz));
            f32x4 z = f32x4{0.f, 0.f, 0.f, 0.f};
            z = __builtin_amdgcn_mfma_f32_16x16x32_bf16(ea0, b0, z, 0, 0, 0);
            z = __builtin_amdgcn_mfma_f32_16x16x32_bf16(ea1, b1, z, 0, 0, 0);
            acc[ct] = z;
        }

        if (m < 2) {                            // Q / K: Tbuf as [s][j]
            #pragma unroll
            for (int ct = 0; ct < 4; ++ct) {
                const int j = ct * 16 + fr;
                const float bb = bias[j];
                if (m == 0) {
                    #pragma unroll
                    for (int r = 0; r < 4; ++r)
                        Tbuf[(sl0 + r) * 72 + j] = f2bf((acc[ct][r] + bb) * 0.125f);
                } else {
                    #pragma unroll
                    for (int r = 0; r < 4; ++r) {
                        float mod = PK[(size_t)(r0 + sl0 + r) * 64 + j];
                        Tbuf[(sl0 + r) * 72 + j] = f2bf((acc[ct][r] + bb) * mod);
                    }
                }
            }
            __syncthreads();
            { // coalesced read-back + 16B global stores
                unsigned short* dst = (m == 0 ? Qb : Kb)
                    + (size_t)(b * Sn + s0 + (t >> 2)) * 64 + (t & 3) * 16;
                u16x8 o0 = *(const u16x8*)&Tbuf[(t >> 2) * 72 + (t & 3) * 16];
                u16x8 o1 = *(const u16x8*)&Tbuf[(t >> 2) * 72 + (t & 3) * 16 + 8];
                *(u16x8*)dst = o0;
                *(u16x8*)(dst + 8) = o1;
            }
            __syncthreads();
        } else {                                // V: Tbuf as [d][s], packed b64 writes
            #pragma unroll
            for (int ct = 0; ct < 4; ++ct) {
                const int j = ct * 16 + fr;
                const float bb = bias[j];
                unsigned long long pk = 0;
                #pragma unroll
                for (int r = 0; r < 4; ++r) {
                    float mod = PV[(size_t)(r0 + sl0 + r) * 64 + j];
                    pk |= (unsigned long long)f2bf((acc[ct][r] + bb) * mod) << (16 * r);
                }
                *(unsigned long long*)&Tbuf[j * 72 + sl0] = pk;
            }
            __syncthreads();
            {
                const int d = t >> 2, seg = t & 3;
                u16x8 o0 = *(const u16x8*)&Tbuf[d * 72 + seg * 16];
                u16x8 o1 = *(const u16x8*)&Tbuf[d * 72 + seg * 16 + 8];
                unsigned short* dst = Vt + (size_t)(b * 64 + d) * Sn + s0 + seg * 16;
                *(u16x8*)dst = o0;
                *(u16x8*)(dst + 8) = o1;
                float s = 0.f;
                #pragma unroll
                for (int i = 0; i < 8; ++i) s += bf2f(o0[i]) + bf2f(o1[i]);
                s += __shfl_xor(s, 1);
                s += __shfl_xor(s, 2);
                if ((t & 3) == 0) atomicAdd(&meanVsum[b * 64 + d], s);
            }
        }
    }
}

// ---------------------------------------------------------------------------
// Kernel 3: flash attention, split-KV, LDS-staged (R5 structure), 128 q-rows
// per block x 8 waves (512 threads).  KV tiles of 64 double-buffered via
// global_load_lds (linear dest + inverse-swizzled source; swizzle
// byte^=((row&7)<<4) on reads).  One 16KB K/V stage now feeds 128 q-rows
// (staging per work halved vs 64-row blocks), and the whole grid (576
// blocks @ 48KB LDS -> 3 blocks/CU, capacity 768) is co-resident: no
// second dispatch pass, no tail.
// Static-offset softmax p = exp(s-16); row-sum l via all-ones-B MFMA;
// masked entries exactly 0.  Block = (b, qi, chunk of <=8 KV tiles),
// qi = 128-row q-tile (0..31); chunks per qi = (qi>>2)+1; grid (144, 4),
// longest chunks dispatched first.  qi<4 (single chunk): final fp32 output
// directly; else normalized bf16 partial + l.
// ---------------------------------------------------------------------------
__global__ __launch_bounds__(512) void LPSAN_attn_kernel(
    const unsigned short* __restrict__ Qb, const unsigned short* __restrict__ Kb,
    const unsigned short* __restrict__ Vt, const unsigned long long* __restrict__ padbits,
    const float* __restrict__ meanVsum,
    unsigned short* __restrict__ Onorm, float* __restrict__ Lp, float* __restrict__ out)
{
    __shared__ unsigned short Klds[2][4096];   // [buf][64 kv x 64 d] swizzled (16KB)
    __shared__ unsigned short Vlds[2][4096];   // [buf][64 d x 64 kv] swizzled (16KB)
    __shared__ unsigned short Plds[8][1024];   // per-wave P 16x64 swizzled (16KB)

    // --- map reversed blockIdx.x -> (qi, c); longest chunks first ---
    // group g (=qi>>2) has 4 q-tiles x (g+1) chunks, base = 2g(g+1)
    int id = 143 - blockIdx.x, g = 0, base = 0;
    while (id >= base + 4 * (g + 1)) { base += 4 * (g + 1); ++g; }
    const int rel = id - base;
    const int qi = 4 * g + rel / (g + 1);
    const int c  = rel % (g + 1);

    const int b = blockIdx.y;
    const int q0 = qi * 128;
    const int t0 = c * 8;
    const int ntiles = 2 * qi + 2;
    const int tcnt = min(8, ntiles - t0);
    const int tid = threadIdx.x;
    const int w = tid >> 6, lane = tid & 63;
    const int fq = lane >> 4, fr = lane & 15;
    const int qw = q0 + w * 16;                 // wave's q-row base

    const unsigned short* Kbase = Kb + b * (Sn * Dn);
    const unsigned short* Vbase = Vt + b * (Dn * Sn);

    // Q A-fragments (row = fr, k = ks*32 + fq*8 + i)
    const s16x8 qf0 = *(const s16x8*)(Qb + (b * Sn + qw + fr) * 64 + fq * 8);
    const s16x8 qf1 = *(const s16x8*)(Qb + (b * Sn + qw + fr) * 64 + 32 + fq * 8);

    s16x8 onesb;                               // all-ones bf16 B operand
    #pragma unroll
    for (int i = 0; i < 8; ++i) onesb[i] = (short)0x3F80;

    f32x4 Oa[4];
    f32x4 lacc = f32x4{0.f, 0.f, 0.f, 0.f};
    #pragma unroll
    for (int i = 0; i < 4; ++i) Oa[i] = f32x4{0.f, 0.f, 0.f, 0.f};

    char* Pw = (char*)&Plds[w][0];

    auto STAGE = [&](int kv0, int bufi) {
        // 8 waves x 64 lanes x 16B = 8KB per buffer; wave w covers bytes
        // [w*1024, w*1024+1024).  LDS dest is wave-uniform base (+lane*16 HW).
        int pos = w * 1024 + lane * 16;
        int row = pos >> 7;
        int cl  = (pos & 127) ^ ((row & 7) << 4);          // inverse-swizzled col byte
        gld16(Kbase + (kv0 + row) * 64 + (cl >> 1),
              (char*)&Klds[bufi][0] + w * 1024);
        gld16(Vbase + row * Sn + kv0 + (cl >> 1),
              (char*)&Vlds[bufi][0] + w * 1024);
    };

    auto COMPUTE = [&](int t, int bufi, bool causal) {
        const char* Kc = (const char*)&Klds[bufi][0];
        const char* Vc = (const char*)&Vlds[bufi][0];
        const int kv0 = t * 64;

        // --- scores: Q (16x64) x K_p^T -> 4 col-tiles of 16 ---
        f32x4 sc[4];
        #pragma unroll
        for (int tl = 0; tl < 4; ++tl) {
            int row = tl * 16 + fr;
            int swz = (row & 7) << 4;
            s16x8 k0 = *(const s16x8*)(Kc + row * 128 + ((fq * 16) ^ swz));
            s16x8 k1 = *(const s16x8*)(Kc + row * 128 + ((64 + fq * 16) ^ swz));
            f32x4 z = f32x4{0.f, 0.f, 0.f, 0.f};
            z = __builtin_amdgcn_mfma_f32_16x16x32_bf16(qf0, k0, z, 0, 0, 0);
            z = __builtin_amdgcn_mfma_f32_16x16x32_bf16(qf1, k1, z, 0, 0, 0);
            sc[tl] = z;
        }

        // --- p = exp(s-16), masked -> 0 ---
        const unsigned long long bits = padbits[b * 64 + t];
        #pragma unroll
        for (int tl = 0; tl < 4; ++tl) {
            const bool pad = (bits >> (tl * 16 + fr)) & 1ull;
            const int col = kv0 + tl * 16 + fr;
            #pragma unroll
            for (int r = 0; r < 4; ++r) {
                float p = __expf(sc[tl][r] - 16.0f);
                bool msk = pad || (causal && (col > (qw + fq * 4 + r)));
                sc[tl][r] = msk ? 0.f : p;
            }
        }

        // --- P -> per-wave LDS (bf16, swizzled) for operand transpose ---
        #pragma unroll
        for (int tl = 0; tl < 4; ++tl) {
            #pragma unroll
            for (int r = 0; r < 4; ++r) {
                int prow = fq * 4 + r;
                int pcb = (tl * 16 + fr) * 2;
                *(unsigned short*)(Pw + prow * 128 + (pcb ^ ((prow & 7) << 4))) = f2bf(sc[tl][r]);
            }
        }
        asm volatile("s_waitcnt lgkmcnt(0)" ::: "memory");
        __builtin_amdgcn_sched_barrier(0);

        // --- PV + row-sum via ones-MFMA ---
        s16x8 pa0 = *(const s16x8*)(Pw + fr * 128 + ((fq * 16) ^ ((fr & 7) << 4)));
        s16x8 pa1 = *(const s16x8*)(Pw + fr * 128 + ((64 + fq * 16) ^ ((fr & 7) << 4)));
        lacc = __builtin_amdgcn_mfma_f32_16x16x32_bf16(pa0, onesb, lacc, 0, 0, 0);
        lacc = __builtin_amdgcn_mfma_f32_16x16x32_bf16(pa1, onesb, lacc, 0, 0, 0);
        #pragma unroll
        for (int dt = 0; dt < 4; ++dt) {
            int row = dt * 16 + fr;
            int swz = (row & 7) << 4;
            s16x8 v0 = *(const s16x8*)(Vc + row * 128 + ((fq * 16) ^ swz));
            s16x8 v1 = *(const s16x8*)(Vc + row * 128 + ((64 + fq * 16) ^ swz));
            Oa[dt] = __builtin_amdgcn_mfma_f32_16x16x32_bf16(pa0, v0, Oa[dt], 0, 0, 0);
            Oa[dt] = __builtin_amdgcn_mfma_f32_16x16x32_bf16(pa1, v1, Oa[dt], 0, 0, 0);
        }
    };

    // --- pipeline: STAGE(next) overlaps COMPUTE(cur); one barrier/tile ---
    STAGE(t0 * 64, 0);
    asm volatile("s_waitcnt vmcnt(0)" ::: "memory");
    __builtin_amdgcn_s_barrier();
    int cur = 0;
    for (int i = 0; i < tcnt - 1; ++i) {
        const int t = t0 + i;
        STAGE((t + 1) * 64, cur ^ 1);
        COMPUTE(t, cur, t >= 2 * qi);          // tiles 2qi, 2qi+1 are diagonal
        asm volatile("s_waitcnt vmcnt(0)" ::: "memory");
        __builtin_amdgcn_s_barrier();
        cur ^= 1;
    }
    {
        const int t = t0 + tcnt - 1;
        COMPUTE(t, cur, t >= 2 * qi);
    }

    if (ntiles <= 8) {
        // --- single chunk (qi<4): final output directly (fp32) ---
        #pragma unroll
        for (int r = 0; r < 4; ++r) {
            int qrow = qw + fq * 4 + r;
            float l = lacc[r];
            bool dead = !(l > 0.f);
            float inv = dead ? 0.f : 1.0f / l;
            #pragma unroll
            for (int dt = 0; dt < 4; ++dt) {
                int d = dt * 16 + fr;
                float val = dead ? meanVsum[b * 64 + d] * (1.0f / (float)Sn)
                                 : Oa[dt][r] * inv;
                out[((size_t)(b * Sn + qrow)) * 64 + d] = val;
            }
        }
    } else {
        // --- partial: normalized O/l (bf16) + l ---
        const int slot = (b * 32 + qi) * 8 + c;
        #pragma unroll
        for (int r = 0; r < 4; ++r) {
            int row128 = w * 16 + fq * 4 + r;  // row within the 128-row q-tile
            float l = lacc[r];
            float inv = (l > 0.f) ? 1.0f / l : 0.f;
            #pragma unroll
            for (int dt = 0; dt < 4; ++dt)
                Onorm[slot * 8192 + row128 * 64 + dt * 16 + fr] = f2bf(Oa[dt][r] * inv);
            if (fr == 0) Lp[slot * 128 + row128] = l;
        }
    }
}

// ---------------------------------------------------------------------------
// Kernel 4: combine partials for qi >= 4 only.  Weights are just l_c.
// Dead row (sum l == 0): reference softmax uniform over ALL S -> meanV.
// Each block: one (b, qi) = 128 rows; thread covers 2 rows x 16 cols.
// ---------------------------------------------------------------------------
__global__ void LPSAN_combine_kernel(
    const unsigned short* __restrict__ Onorm, const float* __restrict__ Lp,
    const float* __restrict__ meanVsum, float* __restrict__ out)
{
    const int qi = 4 + blockIdx.x, b = blockIdx.y;
    const int nch = (qi >> 2) + 1;
    const int t = threadIdx.x;
    const int q4 = t & 3;
    const int slotbase = (b * 32 + qi) * 8;

    #pragma unroll
    for (int rr = 0; rr < 2; ++rr) {
        const int row = (t >> 2) + rr * 64;    // 0..127

        float wsum = 0.f, wgt[8];
        for (int c = 0; c < nch; ++c) { wgt[c] = Lp[(slotbase + c) * 128 + row]; wsum += wgt[c]; }
        const bool dead = !(wsum > 0.f);

        float acc[16];
        #pragma unroll
        for (int j = 0; j < 16; ++j) acc[j] = 0.f;
        for (int c = 0; c < nch; ++c) {
            const unsigned short* src = Onorm + (slotbase + c) * 8192 + row * 64 + q4 * 16;
            u16x8 a0 = *(const u16x8*)(src);
            u16x8 a1 = *(const u16x8*)(src + 8);
            #pragma unroll
            for (int j = 0; j < 8; ++j) { acc[j] += wgt[c] * bf2f(a0[j]); acc[j + 8] += wgt[c] * bf2f(a1[j]); }
        }

        const float inv = dead ? 0.f : 1.0f / wsum;
        float4 o[4];
        #pragma unroll
        for (int v = 0; v < 4; ++v) {
            #pragma unroll
            for (int j = 0; j < 4; ++j) {
                int d = q4 * 16 + v * 4 + j;
                float val = dead ? meanVsum[b * 64 + d] * (1.0f / (float)Sn) : acc[v * 4 + j] * inv;
                ((float*)&o[v])[j] = val;
            }
        }
        float* dst = out + ((size_t)(b * Sn + qi * 128 + row) * 64 + q4 * 16);
        #pragma unroll
        for (int v = 0; v < 4; ++v) *(float4*)(dst + v * 4) = o[v];
    }
}

// ---------------------------------------------------------------------------
extern "C" void kernel_launch(void* const* d_in, const int* in_sizes, int n_in,
                              void* d_out, int out_size, void* d_ws, size_t ws_size,
                              hipStream_t stream) {
    const float* E  = (const float*)d_in[0];
    const float* PK = (const float*)d_in[1];
    const float* PV = (const float*)d_in[2];
    const float* Wq = (const float*)d_in[3];
    const float* bq = (const float*)d_in[4];
    const float* Wk = (const float*)d_in[5];
    const float* bk = (const float*)d_in[6];
    const float* Wv = (const float*)d_in[7];
    const float* bv = (const float*)d_in[8];
    const unsigned char* pm = (const unsigned char*)d_in[9];

    char* ws = (char*)d_ws;
    const size_t SZ = (size_t)Bn * Sn * Dn * sizeof(unsigned short);   // 2 MB each
    unsigned short* Qb = (unsigned short*)(ws);
    unsigned short* Kb = (unsigned short*)(ws + SZ);
    unsigned short* Vt = (unsigned short*)(ws + 2 * SZ);
    unsigned short* On = (unsigned short*)(ws + 3 * SZ);               // 16 MB
    const size_t ONB = (size_t)Bn * 32 * 8 * 8192 * sizeof(unsigned short);
    float* Lp = (float*)(ws + 3 * SZ + ONB);                           // 512 KB
    unsigned long long* padbits = (unsigned long long*)(ws + 3 * SZ + ONB + 524288);
    float* meanVsum = (float*)(ws + 3 * SZ + ONB + 524288 + 4096);
    float* out = (float*)d_out;

    hipLaunchKernelGGL(LPSAN_init_kernel, dim3(9), dim3(256), 0, stream, pm, padbits, meanVsum);
    hipLaunchKernelGGL(LPSAN_proj_kernel, dim3(Bn * Sn / 64), dim3(256), 0, stream,
                       E, PK, PV, Wq, bq, Wk, bk, Wv, bv, Qb, Kb, Vt, meanVsum);
    hipLaunchKernelGGL(LPSAN_attn_kernel, dim3(144, Bn), dim3(512), 0, stream,
                       Qb, Kb, Vt, padbits, meanVsum, On, Lp, out);
    hipLaunchKernelGGL(LPSAN_combine_kernel, dim3(28, Bn), dim3(256), 0, stream,
                       On, Lp, meanVsum, out);
}

// Round 9
// 122.663 us; speedup vs baseline: 1.6558x; 1.1269x over previous
//
#include <hip/hip_runtime.h>
#include <hip/hip_bf16.h>

#define Bn 4
#define Sn 4096
#define Dn 64

typedef short          s16x8 __attribute__((ext_vector_type(8)));
typedef unsigned short u16x8 __attribute__((ext_vector_type(8)));
typedef float          f32x4 __attribute__((ext_vector_type(4)));

typedef __attribute__((address_space(1))) const void gas_void;
typedef __attribute__((address_space(3))) void       las_void;

__device__ __forceinline__ unsigned short f2bf(float f) {
    unsigned u = __float_as_uint(f);
    u = u + 0x7fffu + ((u >> 16) & 1u);   // RNE
    return (unsigned short)(u >> 16);
}
__device__ __forceinline__ float bf2f(unsigned short h) {
    return __uint_as_float(((unsigned)h) << 16);
}
__device__ __forceinline__ unsigned long long pack4(float4 x) {
    return (unsigned long long)f2bf(x.x)
         | ((unsigned long long)f2bf(x.y) << 16)
         | ((unsigned long long)f2bf(x.z) << 32)
         | ((unsigned long long)f2bf(x.w) << 48);
}
__device__ __forceinline__ void gld16(const void* g, void* l) {
    __builtin_amdgcn_global_load_lds((gas_void*)g, (las_void*)l, 16, 0, 0);
}

// ---------------------------------------------------------------------------
// Kernel 1 (init): 9 blocks x 256 threads.
//   blocks 0..7 : pack pad_mask into padbits (32 words of 64 cols each).
//   block 8     : zero meanVsum (256 floats).
// ---------------------------------------------------------------------------
__global__ void LPSAN_init_kernel(const unsigned char* pm, unsigned long long* padbits,
                                  float* meanVsum) {
    const int k = blockIdx.x, t = threadIdx.x;
    if (k == 8) { meanVsum[t] = 0.f; return; }

    __shared__ unsigned nzs;
    if (t == 0) nzs = 0u;
    __syncthreads();
    { // detection: bytes [k*2048, (k+1)*2048) -- inside first 16KB, safe always
        const uint2* p2 = (const uint2*)(pm + k * 2048);
        uint2 x = p2[t];
        unsigned acc = (x.x & 0xFFFFFF00u) | (x.y & 0xFFFFFF00u);
        if (acc) atomicOr(&nzs, 1u);
    }
    __syncthreads();
    if (t >= 32) return;
    const int wi = k * 32 + t;              // padbits word index
    unsigned long long bits = 0ull;
    if (nzs) {                              // uint8 storage: 64 bytes
        const uint4* p4 = (const uint4*)(pm + wi * 64);
        #pragma unroll
        for (int q = 0; q < 4; ++q) {
            uint4 x = p4[q];
            unsigned w[4] = { x.x, x.y, x.z, x.w };
            #pragma unroll
            for (int wj = 0; wj < 4; ++wj)
                #pragma unroll
                for (int bb = 0; bb < 4; ++bb)
                    bits |= (unsigned long long)(((w[wj] >> (8 * bb)) & 0xFFu) != 0u)
                            << (q * 16 + wj * 4 + bb);
        }
    } else {                                // int32 storage: 64 ints
        const uint4* p4 = (const uint4*)pm + wi * 16;
        #pragma unroll
        for (int q = 0; q < 16; ++q) {
            uint4 x = p4[q];
            bits |= (unsigned long long)(x.x != 0u) << (q * 4);
            bits |= (unsigned long long)(x.y != 0u) << (q * 4 + 1);
            bits |= (unsigned long long)(x.z != 0u) << (q * 4 + 2);
            bits |= (unsigned long long)(x.w != 0u) << (q * 4 + 3);
        }
    }
    padbits[wi] = bits;
}

// ---------------------------------------------------------------------------
// Kernel 2: MFMA QKV projection.  64 rows/block, 256 blocks, 4 waves x 16
// rows.  E and W staged as bf16 in LDS with XOR swizzle ^((row&7)<<4); 8
// MFMA (16x16x32) per matrix per wave.  Epilogue through padded LDS for
// coalesced 16B stores.  Also accumulates meanVsum[b*64+d] = sum_s V_p.
// ---------------------------------------------------------------------------
__global__ void LPSAN_proj_kernel(
    const float* __restrict__ E, const float* __restrict__ PK, const float* __restrict__ PV,
    const float* __restrict__ Wq, const float* __restrict__ bq,
    const float* __restrict__ Wk, const float* __restrict__ bk,
    const float* __restrict__ Wv, const float* __restrict__ bv,
    unsigned short* __restrict__ Qb, unsigned short* __restrict__ Kb,
    unsigned short* __restrict__ Vt, float* __restrict__ meanVsum)
{
    __shared__ unsigned short Ebf[4096];        // [64][64] bf16, swizzled (8KB)
    __shared__ unsigned short Wbf[3][4096];     // swizzled (24KB)
    __shared__ unsigned short Tbuf[64 * 72];    // transpose staging (9KB)

    const int t = threadIdx.x;                  // 256 threads
    const int r0 = blockIdx.x * 64;
    const int b  = r0 >> 12;
    const int s0 = r0 & (Sn - 1);
    const int w = t >> 6, lane = t & 63;
    const int fq = lane >> 4, fr = lane & 15;

    { // stage E and W: fp32 -> bf16, swizzled 8B writes
        const float4* Eg = (const float4*)(E + (size_t)r0 * 64);
        #pragma unroll
        for (int v = 0; v < 4; ++v) {
            int f = t + v * 256;
            float4 x = Eg[f];
            int row = f >> 4, c4 = f & 15;
            *(unsigned long long*)((char*)Ebf + row * 128 + ((c4 * 8) ^ ((row & 7) << 4))) = pack4(x);
        }
        #pragma unroll
        for (int m = 0; m < 3; ++m) {
            const float4* Wg = (const float4*)(m == 0 ? Wq : m == 1 ? Wk : Wv);
            #pragma unroll
            for (int v = 0; v < 4; ++v) {
                int f = t + v * 256;
                float4 x = Wg[f];
                int row = f >> 4, c4 = f & 15;
                *(unsigned long long*)((char*)Wbf[m] + row * 128 + ((c4 * 8) ^ ((row & 7) << 4))) = pack4(x);
            }
        }
    }
    __syncthreads();

    // A-frags: E[row = w*16+fr][k = ks*32 + fq*8+i]
    const int  arow = w * 16 + fr;
    const int  swz  = (fr & 7) << 4;
    const char* Ec = (const char*)Ebf;
    const s16x8 ea0 = *(const s16x8*)(Ec + arow * 128 + ((fq * 16) ^ swz));
    const s16x8 ea1 = *(const s16x8*)(Ec + arow * 128 + ((64 + fq * 16) ^ swz));

    const int sl0 = w * 16 + fq * 4;            // lane's first local output row

    for (int m = 0; m < 3; ++m) {
        const char*  Wc   = (const char*)Wbf[m];
        const float* bias = (m == 0) ? bq : (m == 1) ? bk : bv;

        f32x4 acc[4];
        #pragma unroll
        for (int ct = 0; ct < 4; ++ct) {        // B-frag: W[j=ct*16+fr][k=fq*8+i]
            const int brow = ct * 16 + fr;
            s16x8 b0 = *(const s16x8*)(Wc + brow * 128 + ((fq * 16) ^ swz));
            s16x8 b1 = *(const s16x8*)(Wc + brow * 128 + ((64 + fq * 16) ^ swz));
            f32x4 z = f32x4{0.f, 0.f, 0.f, 0.f};
            z = __builtin_amdgcn_mfma_f32_16x16x32_bf16(ea0, b0, z, 0, 0, 0);
            z = __builtin_amdgcn_mfma_f32_16x16x32_bf16(ea1, b1, z, 0, 0, 0);
            acc[ct] = z;
        }

        if (m < 2) {                            // Q / K: Tbuf as [s][j]
            #pragma unroll
            for (int ct = 0; ct < 4; ++ct) {
                const int j = ct * 16 + fr;
                const float bb = bias[j];
                if (m == 0) {
                    #pragma unroll
                    for (int r = 0; r < 4; ++r)
                        Tbuf[(sl0 + r) * 72 + j] = f2bf((acc[ct][r] + bb) * 0.125f);
                } else {
                    #pragma unroll
                    for (int r = 0; r < 4; ++r) {
                        float mod = PK[(size_t)(r0 + sl0 + r) * 64 + j];
                        Tbuf[(sl0 + r) * 72 + j] = f2bf((acc[ct][r] + bb) * mod);
                    }
                }
            }
            __syncthreads();
            { // coalesced read-back + 16B global stores
                unsigned short* dst = (m == 0 ? Qb : Kb)
                    + (size_t)(b * Sn + s0 + (t >> 2)) * 64 + (t & 3) * 16;
                u16x8 o0 = *(const u16x8*)&Tbuf[(t >> 2) * 72 + (t & 3) * 16];
                u16x8 o1 = *(const u16x8*)&Tbuf[(t >> 2) * 72 + (t & 3) * 16 + 8];
                *(u16x8*)dst = o0;
                *(u16x8*)(dst + 8) = o1;
            }
            __syncthreads();
        } else {                                // V: Tbuf as [d][s], packed b64 writes
            #pragma unroll
            for (int ct = 0; ct < 4; ++ct) {
                const int j = ct * 16 + fr;
                const float bb = bias[j];
                unsigned long long pk = 0;
                #pragma unroll
                for (int r = 0; r < 4; ++r) {
                    float mod = PV[(size_t)(r0 + sl0 + r) * 64 + j];
                    pk |= (unsigned long long)f2bf((acc[ct][r] + bb) * mod) << (16 * r);
                }
                *(unsigned long long*)&Tbuf[j * 72 + sl0] = pk;
            }
            __syncthreads();
            {
                const int d = t >> 2, seg = t & 3;
                u16x8 o0 = *(const u16x8*)&Tbuf[d * 72 + seg * 16];
                u16x8 o1 = *(const u16x8*)&Tbuf[d * 72 + seg * 16 + 8];
                unsigned short* dst = Vt + (size_t)(b * 64 + d) * Sn + s0 + seg * 16;
                *(u16x8*)dst = o0;
                *(u16x8*)(dst + 8) = o1;
                float s = 0.f;
                #pragma unroll
                for (int i = 0; i < 8; ++i) s += bf2f(o0[i]) + bf2f(o1[i]);
                s += __shfl_xor(s, 1);
                s += __shfl_xor(s, 2);
                if ((t & 3) == 0) atomicAdd(&meanVsum[b * 64 + d], s);
            }
        }
    }
}

// ---------------------------------------------------------------------------
// Kernel 3: flash attention, split-KV, LDS-staged (R5 geometry: 64 q-rows,
// 4 waves, KV tiles of 64 double-buffered via global_load_lds, grid (288,4)
// longest-chunk-first).  Static-offset softmax p = exp(s-16); row-sum l via
// all-ones-B MFMA; masked entries exactly 0.
// NEW vs R5: partials ACCUMULATE via fp32 atomicAdd into Oacc/Lsum (all
// chunks share the e^-16 scale, so plain sums combine exactly); the bf16
// Onorm round-trip and the combine kernel are deleted.  qt<8 single-chunk
// rows still write final output directly.
// ---------------------------------------------------------------------------
__global__ void LPSAN_attn_kernel(
    const unsigned short* __restrict__ Qb, const unsigned short* __restrict__ Kb,
    const unsigned short* __restrict__ Vt, const unsigned long long* __restrict__ padbits,
    const float* __restrict__ meanVsum,
    float* __restrict__ Oacc, float* __restrict__ Lsum, float* __restrict__ out)
{
    __shared__ unsigned short Klds[2][4096];   // [buf][64 kv x 64 d] swizzled
    __shared__ unsigned short Vlds[2][4096];   // [buf][64 d x 64 kv] swizzled
    __shared__ unsigned short Plds[4][1024];   // per-wave P 16x64 swizzled

    // --- map reversed blockIdx.x -> (qt, c); longest chunks first ---
    int id = 287 - blockIdx.x, g = 0, base = 0;
    while (id >= base + 8 * (g + 1)) { base += 8 * (g + 1); ++g; }
    const int rel = id - base;
    const int qt = 8 * g + rel / (g + 1);
    const int c  = rel % (g + 1);

    const int b = blockIdx.y;
    const int q0 = qt * 64;
    const int t0 = c * 8;
    const int tcnt = min(8, qt + 1 - t0);
    const int tid = threadIdx.x;
    const int w = tid >> 6, lane = tid & 63;
    const int fq = lane >> 4, fr = lane & 15;
    const int qw = q0 + w * 16;

    const unsigned short* Kbase = Kb + b * (Sn * Dn);
    const unsigned short* Vbase = Vt + b * (Dn * Sn);

    const s16x8 qf0 = *(const s16x8*)(Qb + (b * Sn + qw + fr) * 64 + fq * 8);
    const s16x8 qf1 = *(const s16x8*)(Qb + (b * Sn + qw + fr) * 64 + 32 + fq * 8);

    s16x8 onesb;                               // all-ones bf16 B operand
    #pragma unroll
    for (int i = 0; i < 8; ++i) onesb[i] = (short)0x3F80;

    f32x4 Oa[4];
    f32x4 lacc = f32x4{0.f, 0.f, 0.f, 0.f};
    #pragma unroll
    for (int i = 0; i < 4; ++i) Oa[i] = f32x4{0.f, 0.f, 0.f, 0.f};

    char* Pw = (char*)&Plds[w][0];

    auto STAGE = [&](int kv0, int bufi) {
        #pragma unroll
        for (int cc = 0; cc < 2; ++cc) {
            int pos = w * 2048 + cc * 1024 + lane * 16;
            int row = pos >> 7;
            int cl  = (pos & 127) ^ ((row & 7) << 4);
            gld16(Kbase + (kv0 + row) * 64 + (cl >> 1),
                  (char*)&Klds[bufi][0] + w * 2048 + cc * 1024);
            gld16(Vbase + row * Sn + kv0 + (cl >> 1),
                  (char*)&Vlds[bufi][0] + w * 2048 + cc * 1024);
        }
    };

    auto COMPUTE = [&](int t, int bufi, bool causal) {
        const char* Kc = (const char*)&Klds[bufi][0];
        const char* Vc = (const char*)&Vlds[bufi][0];
        const int kv0 = t * 64;

        // --- scores ---
        f32x4 sc[4];
        #pragma unroll
        for (int tl = 0; tl < 4; ++tl) {
            int row = tl * 16 + fr;
            int swz = (row & 7) << 4;
            s16x8 k0 = *(const s16x8*)(Kc + row * 128 + ((fq * 16) ^ swz));
            s16x8 k1 = *(const s16x8*)(Kc + row * 128 + ((64 + fq * 16) ^ swz));
            f32x4 z = f32x4{0.f, 0.f, 0.f, 0.f};
            z = __builtin_amdgcn_mfma_f32_16x16x32_bf16(qf0, k0, z, 0, 0, 0);
            z = __builtin_amdgcn_mfma_f32_16x16x32_bf16(qf1, k1, z, 0, 0, 0);
            sc[tl] = z;
        }

        // --- p = exp(s-16), masked -> 0 ---
        const unsigned long long bits = padbits[b * 64 + t];
        #pragma unroll
        for (int tl = 0; tl < 4; ++tl) {
            const bool pad = (bits >> (tl * 16 + fr)) & 1ull;
            const int col = kv0 + tl * 16 + fr;
            #pragma unroll
            for (int r = 0; r < 4; ++r) {
                float p = __expf(sc[tl][r] - 16.0f);
                bool msk = pad || (causal && (col > (qw + fq * 4 + r)));
                sc[tl][r] = msk ? 0.f : p;
            }
        }

        // --- P -> per-wave LDS (bf16, swizzled) for operand transpose ---
        #pragma unroll
        for (int tl = 0; tl < 4; ++tl) {
            #pragma unroll
            for (int r = 0; r < 4; ++r) {
                int prow = fq * 4 + r;
                int pcb = (tl * 16 + fr) * 2;
                *(unsigned short*)(Pw + prow * 128 + (pcb ^ ((prow & 7) << 4))) = f2bf(sc[tl][r]);
            }
        }
        asm volatile("s_waitcnt lgkmcnt(0)" ::: "memory");
        __builtin_amdgcn_sched_barrier(0);

        // --- PV + row-sum via ones-MFMA ---
        s16x8 pa0 = *(const s16x8*)(Pw + fr * 128 + ((fq * 16) ^ ((fr & 7) << 4)));
        s16x8 pa1 = *(const s16x8*)(Pw + fr * 128 + ((64 + fq * 16) ^ ((fr & 7) << 4)));
        lacc = __builtin_amdgcn_mfma_f32_16x16x32_bf16(pa0, onesb, lacc, 0, 0, 0);
        lacc = __builtin_amdgcn_mfma_f32_16x16x32_bf16(pa1, onesb, lacc, 0, 0, 0);
        #pragma unroll
        for (int dt = 0; dt < 4; ++dt) {
            int row = dt * 16 + fr;
            int swz = (row & 7) << 4;
            s16x8 v0 = *(const s16x8*)(Vc + row * 128 + ((fq * 16) ^ swz));
            s16x8 v1 = *(const s16x8*)(Vc + row * 128 + ((64 + fq * 16) ^ swz));
            Oa[dt] = __builtin_amdgcn_mfma_f32_16x16x32_bf16(pa0, v0, Oa[dt], 0, 0, 0);
            Oa[dt] = __builtin_amdgcn_mfma_f32_16x16x32_bf16(pa1, v1, Oa[dt], 0, 0, 0);
        }
    };

    // --- pipeline: STAGE(next) overlaps COMPUTE(cur); one barrier/tile ---
    STAGE(t0 * 64, 0);
    asm volatile("s_waitcnt vmcnt(0)" ::: "memory");
    __builtin_amdgcn_s_barrier();
    int cur = 0;
    for (int i = 0; i < tcnt - 1; ++i) {
        STAGE((t0 + i + 1) * 64, cur ^ 1);
        COMPUTE(t0 + i, cur, false);
        asm volatile("s_waitcnt vmcnt(0)" ::: "memory");
        __builtin_amdgcn_s_barrier();
        cur ^= 1;
    }
    COMPUTE(t0 + tcnt - 1, cur, (t0 + tcnt - 1) == qt);

    if (qt < 8) {
        // --- single chunk: final output directly (fp32) ---
        #pragma unroll
        for (int r = 0; r < 4; ++r) {
            int qrow = qw + fq * 4 + r;
            float l = lacc[r];
            bool dead = !(l > 0.f);
            float inv = dead ? 0.f : 1.0f / l;
            #pragma unroll
            for (int dt = 0; dt < 4; ++dt) {
                int d = dt * 16 + fr;
                float val = dead ? meanVsum[b * 64 + d] * (1.0f / (float)Sn)
                                 : Oa[dt][r] * inv;
                out[((size_t)(b * Sn + qrow)) * 64 + d] = val;
            }
        }
    } else {
        // --- accumulate unnormalized partial into fp32 Oacc/Lsum ---
        #pragma unroll
        for (int r = 0; r < 4; ++r) {
            int qrow = qw + fq * 4 + r;
            if (fr == 0) atomicAdd(&Lsum[b * Sn + qrow], lacc[r]);
            #pragma unroll
            for (int dt = 0; dt < 4; ++dt)
                atomicAdd(&Oacc[((size_t)(b * Sn + qrow)) * 64 + dt * 16 + fr], Oa[dt][r]);
        }
    }
}

// ---------------------------------------------------------------------------
// Kernel 4 (normalize): rows of qt >= 8 only.  out = Oacc / Lsum.
// Dead row (Lsum == 0): reference softmax uniform over ALL S -> meanV.
// Grid (56, 4) x 256 threads; thread = 1 row x 16 d.
// ---------------------------------------------------------------------------
__global__ void LPSAN_norm_kernel(
    const float* __restrict__ Oacc, const float* __restrict__ Lsum,
    const float* __restrict__ meanVsum, float* __restrict__ out)
{
    const int qt = 8 + blockIdx.x, b = blockIdx.y;
    const int t = threadIdx.x;
    const int row = t >> 2, q4 = t & 3;
    const int qrow = qt * 64 + row;

    const float l = Lsum[b * Sn + qrow];
    const bool dead = !(l > 0.f);
    const float inv = dead ? 0.f : 1.0f / l;

    const float* src = Oacc + ((size_t)(b * Sn + qrow)) * 64 + q4 * 16;
    float*       dst = out  + ((size_t)(b * Sn + qrow)) * 64 + q4 * 16;
    #pragma unroll
    for (int v = 0; v < 4; ++v) {
        float4 x = *(const float4*)(src + v * 4);
        float4 o;
        if (dead) {
            const float* mv = meanVsum + b * 64 + q4 * 16 + v * 4;
            o.x = mv[0] * (1.0f / (float)Sn);
            o.y = mv[1] * (1.0f / (float)Sn);
            o.z = mv[2] * (1.0f / (float)Sn);
            o.w = mv[3] * (1.0f / (float)Sn);
        } else {
            o.x = x.x * inv; o.y = x.y * inv; o.z = x.z * inv; o.w = x.w * inv;
        }
        *(float4*)(dst + v * 4) = o;
    }
}

// ---------------------------------------------------------------------------
extern "C" void kernel_launch(void* const* d_in, const int* in_sizes, int n_in,
                              void* d_out, int out_size, void* d_ws, size_t ws_size,
                              hipStream_t stream) {
    const float* E  = (const float*)d_in[0];
    const float* PK = (const float*)d_in[1];
    const float* PV = (const float*)d_in[2];
    const float* Wq = (const float*)d_in[3];
    const float* bq = (const float*)d_in[4];
    const float* Wk = (const float*)d_in[5];
    const float* bk = (const float*)d_in[6];
    const float* Wv = (const float*)d_in[7];
    const float* bv = (const float*)d_in[8];
    const unsigned char* pm = (const unsigned char*)d_in[9];

    char* ws = (char*)d_ws;
    const size_t SZ = (size_t)Bn * Sn * Dn * sizeof(unsigned short);   // 2 MB each
    const size_t OB = (size_t)Bn * Sn * Dn * sizeof(float);            // 4 MB
    const size_t LB = (size_t)Bn * Sn * sizeof(float);                 // 64 KB
    unsigned short* Qb = (unsigned short*)(ws);
    unsigned short* Kb = (unsigned short*)(ws + SZ);
    unsigned short* Vt = (unsigned short*)(ws + 2 * SZ);
    float* Oacc = (float*)(ws + 3 * SZ);
    float* Lsum = (float*)(ws + 3 * SZ + OB);
    unsigned long long* padbits = (unsigned long long*)(ws + 3 * SZ + OB + LB);
    float* meanVsum = (float*)(ws + 3 * SZ + OB + LB + 4096);
    float* out = (float*)d_out;

    hipMemsetAsync(Oacc, 0, OB + LB, stream);   // zero Oacc + Lsum (contiguous)
    hipLaunchKernelGGL(LPSAN_init_kernel, dim3(9), dim3(256), 0, stream, pm, padbits, meanVsum);
    hipLaunchKernelGGL(LPSAN_proj_kernel, dim3(Bn * Sn / 64), dim3(256), 0, stream,
                       E, PK, PV, Wq, bq, Wk, bk, Wv, bv, Qb, Kb, Vt, meanVsum);
    hipLaunchKernelGGL(LPSAN_attn_kernel, dim3(288, Bn), dim3(256), 0, stream,
                       Qb, Kb, Vt, padbits, meanVsum, Oacc, Lsum, out);
    hipLaunchKernelGGL(LPSAN_norm_kernel, dim3(56, Bn), dim3(256), 0, stream,
                       Oacc, Lsum, meanVsum, out);
}